// Round 10
// baseline (235.888 us; speedup 1.0000x reference)
//
#include <hip/hip_runtime.h>

typedef _Float16 f16;
typedef __attribute__((ext_vector_type(8))) _Float16 f16x8;
typedef __attribute__((ext_vector_type(4))) _Float16 f16x4;
typedef __attribute__((ext_vector_type(2))) _Float16 f16x2;
typedef __attribute__((ext_vector_type(4))) float f32x4;

#define DEVINL __device__ __forceinline__

DEVINL void gload16(const void* g, void* l) {
  __builtin_amdgcn_global_load_lds(
      (const __attribute__((address_space(1))) void*)g,
      (__attribute__((address_space(3))) void*)l, 16, 0, 0);
}

DEVINL f32x4 mfma16(f16x8 a, f16x8 b, f32x4 c) {
  return __builtin_amdgcn_mfma_f32_16x16x32_f16(a, b, c, 0, 0, 0);
}

// packed f32x2 -> f16x2 (RTZ); builtin returns __fp16x2, bit-identical layout
DEVINL f16x2 cvt_pk(float a, float b) {
  return __builtin_bit_cast(f16x2, __builtin_amdgcn_cvt_pkrtz(a, b));
}

// ---------------------------------------------------------------- converts
// One launch for Wq|Wk|Wv -> Wcat and Wo -> Wob (4 x 589824 f32 -> f16).
__global__ __launch_bounds__(256) void convert_w(const float* __restrict__ wq,
                                                 const float* __restrict__ wk,
                                                 const float* __restrict__ wv,
                                                 const float* __restrict__ wo,
                                                 f16* __restrict__ wcat,
                                                 f16* __restrict__ wob) {
  int seg = blockIdx.x / 576;
  int i = ((blockIdx.x % 576) * 256 + threadIdx.x) * 4;
  const float* src = seg == 0 ? wq : (seg == 1 ? wk : (seg == 2 ? wv : wo));
  f16* dst = seg < 3 ? wcat + seg * 589824 : wob;
  f32x4 v = *(const f32x4*)(src + i);
  f16x4 o = {(f16)v[0], (f16)v[1], (f16)v[2], (f16)v[3]};
  *(f16x4*)(dst + i) = o;
}

// x (B,768,2048) f32 -> Xt (B,2048,768) f16   (64x64 tiles via padded LDS)
__global__ __launch_bounds__(256) void transpose_x(const float* __restrict__ x,
                                                   f16* __restrict__ xt) {
  __shared__ __attribute__((aligned(16))) f16 T[64 * 66];
  const int b = blockIdx.z, c0 = blockIdx.y * 64, n0 = blockIdx.x * 64;
  const int t = threadIdx.x;
  const float* xb = x + (size_t)b * 768 * 2048;
#pragma unroll
  for (int r = 0; r < 4; ++r) {
    int chunk = r * 256 + t;
    int row = chunk >> 4, c4 = (chunk & 15) * 4;
    f32x4 v = *(const f32x4*)&xb[(size_t)(c0 + row) * 2048 + n0 + c4];
#pragma unroll
    for (int e = 0; e < 4; ++e) T[row * 66 + c4 + e] = (f16)v[e];
  }
  __syncthreads();
  f16* xtb = xt + (size_t)b * 2048 * 768;
  int n = t >> 2, cp = (t & 3) * 16;
  __attribute__((aligned(16))) f16 vals[16];
#pragma unroll
  for (int j = 0; j < 16; ++j) vals[j] = T[(cp + j) * 66 + n];
  *(f16x8*)&xtb[(size_t)(n0 + n) * 768 + c0 + cp] = *(const f16x8*)&vals[0];
  *(f16x8*)&xtb[(size_t)(n0 + n) * 768 + c0 + cp + 8] = *(const f16x8*)&vals[8];
}

// ---------------------------------------------------------------- GEMM (QKV)
// C[m0+128][n0+128] = A(M,768) @ Bt(2048,768)^T   per batch z.
// m0<1536 -> transposed f16 store into qkt (B,2048,1536)
// m0>=1536 -> direct f16 store into vbuf (B,768,2048)
__global__ __launch_bounds__(256, 2)
void gemm_kernel(const f16* __restrict__ A, const f16* __restrict__ Bt,
                 f16* __restrict__ qkt, f16* __restrict__ vbuf) {
  constexpr int K = 768;
  const int b = blockIdx.z;
  const int n0 = blockIdx.x * 128;
  const int m0 = blockIdx.y * 128;
  const int t = threadIdx.x;
  const int lane = t & 63, w = t >> 6, g = lane >> 4, lo = lane & 15;
  const int wm = (w >> 1) * 64, wn = (w & 1) * 64;

  __shared__ __attribute__((aligned(16))) f16 smem[16384];
  f16* As = smem;          // [128 m][64 k], chunk-swizzled (c8 ^= row&7)
  f16* Bs = smem + 8192;   // [128 n][64 k], same swizzle

  const f16* Ab = A + (size_t)m0 * K;
  const f16* Bb = Bt + (size_t)b * 2048 * K + (size_t)n0 * K;

  const f32x4 zf = {0.f, 0.f, 0.f, 0.f};
  f32x4 acc[4][4];
#pragma unroll
  for (int i = 0; i < 4; ++i)
#pragma unroll
    for (int j = 0; j < 4; ++j) acc[i][j] = zf;

  for (int kt = 0; kt < K; kt += 64) {
    __syncthreads();
#pragma unroll
    for (int r = 0; r < 4; ++r) {
      int chunk = r * 256 + t;
      int row = chunk >> 3;
      int c8 = (chunk & 7) ^ (row & 7);
      gload16(Ab + (size_t)row * K + kt + c8 * 8, As + chunk * 8);
    }
#pragma unroll
    for (int r = 0; r < 4; ++r) {
      int chunk = r * 256 + t;
      int row = chunk >> 3;
      int c8 = (chunk & 7) ^ (row & 7);
      gload16(Bb + (size_t)row * K + kt + c8 * 8, Bs + chunk * 8);
    }
    __syncthreads();
#pragma unroll
    for (int kk = 0; kk < 2; ++kk) {
      f16x8 af[4], bfr[4];
#pragma unroll
      for (int i = 0; i < 4; ++i) {
        int row = wm + i * 16 + lo;
        af[i] = *(const f16x8*)&As[row * 64 + (((kk * 4 + g) ^ (row & 7)) * 8)];
      }
#pragma unroll
      for (int j = 0; j < 4; ++j) {
        int col = wn + j * 16 + lo;
        bfr[j] = *(const f16x8*)&Bs[col * 64 + (((kk * 4 + g) ^ (col & 7)) * 8)];
      }
#pragma unroll
      for (int i = 0; i < 4; ++i)
#pragma unroll
        for (int j = 0; j < 4; ++j)
          acc[i][j] = mfma16(af[i], bfr[j], acc[i][j]);
    }
  }

  if (m0 >= 1536) {
    f16* Vb = vbuf + (size_t)b * 768 * 2048;
#pragma unroll
    for (int i = 0; i < 4; ++i) {
      int row = m0 - 1536 + wm + i * 16 + g * 4;
#pragma unroll
      for (int j = 0; j < 4; ++j) {
        int col = n0 + wn + j * 16 + lo;
#pragma unroll
        for (int r2 = 0; r2 < 4; ++r2)
          Vb[(size_t)(row + r2) * 2048 + col] = (f16)acc[i][j][r2];
      }
    }
  } else {
    // transpose-store via LDS: QKt[b][n0+n][m0 + m] = C[m][n]
    __syncthreads();
    f16* T = smem;  // [128 n][128 m], chunk16-swizzled (c ^= n&15)
#pragma unroll
    for (int i = 0; i < 4; ++i)
#pragma unroll
      for (int j = 0; j < 4; ++j) {
        int nl = wn + j * 16 + lo;
#pragma unroll
        for (int r2 = 0; r2 < 4; ++r2) {
          int ml = wm + i * 16 + g * 4 + r2;
          T[nl * 128 + (((ml >> 3) ^ (nl & 15)) * 8) + (ml & 7)] =
              (f16)acc[i][j][r2];
        }
      }
    __syncthreads();
    f16* Qb = qkt + (size_t)b * 2048 * 1536;
    int n = t >> 1, half = t & 1;
#pragma unroll
    for (int c = 0; c < 8; ++c) {
      int chunk = half * 8 + c;
      f16x8 v = *(const f16x8*)&T[n * 128 + ((chunk ^ (n & 15)) * 8)];
      *(f16x8*)&Qb[(size_t)(n0 + n) * 1536 + m0 + chunk * 8] = v;
    }
  }
}

// ---------------------------------------------------------------- GEMM (out)
// Round-10: output projection with 128(m) x 64(n) tiles so grid = (32,6,4)
// = 768 blocks = exactly 3/CU (was 384 = 1.5/CU -> 75% utilization).
// A = Wo (1.2 MB, L2-resident; extra refetch free), B-traffic unchanged.
__global__ __launch_bounds__(256, 3)
void gemm_out(const f16* __restrict__ A, const f16* __restrict__ Bt,
              float* __restrict__ outp) {
  constexpr int K = 768;
  const int b = blockIdx.z;
  const int n0 = blockIdx.x * 64;
  const int m0 = blockIdx.y * 128;
  const int t = threadIdx.x;
  const int lane = t & 63, w = t >> 6, g = lane >> 4, lo = lane & 15;
  const int wm = (w >> 1) * 64, wn = (w & 1) * 32;

  __shared__ __attribute__((aligned(16))) f16 smem[12288];
  f16* As = smem;          // [128 m][64 k], chunk-swizzled
  f16* Bs = smem + 8192;   // [64 n][64 k], chunk-swizzled

  const f16* Ab = A + (size_t)m0 * K;
  const f16* Bb = Bt + (size_t)b * 2048 * K + (size_t)n0 * K;

  const f32x4 zf = {0.f, 0.f, 0.f, 0.f};
  f32x4 acc[4][2];
#pragma unroll
  for (int i = 0; i < 4; ++i)
#pragma unroll
    for (int j = 0; j < 2; ++j) acc[i][j] = zf;

  for (int kt = 0; kt < K; kt += 64) {
    __syncthreads();
#pragma unroll
    for (int r = 0; r < 4; ++r) {
      int chunk = r * 256 + t;
      int row = chunk >> 3;
      int c8 = (chunk & 7) ^ (row & 7);
      gload16(Ab + (size_t)row * K + kt + c8 * 8, As + chunk * 8);
    }
#pragma unroll
    for (int r = 0; r < 2; ++r) {
      int chunk = r * 256 + t;
      int row = chunk >> 3;
      int c8 = (chunk & 7) ^ (row & 7);
      gload16(Bb + (size_t)row * K + kt + c8 * 8, Bs + chunk * 8);
    }
    __syncthreads();
#pragma unroll
    for (int kk = 0; kk < 2; ++kk) {
      f16x8 af[4], bfr[2];
#pragma unroll
      for (int i = 0; i < 4; ++i) {
        int row = wm + i * 16 + lo;
        af[i] = *(const f16x8*)&As[row * 64 + (((kk * 4 + g) ^ (row & 7)) * 8)];
      }
#pragma unroll
      for (int j = 0; j < 2; ++j) {
        int col = wn + j * 16 + lo;
        bfr[j] = *(const f16x8*)&Bs[col * 64 + (((kk * 4 + g) ^ (col & 7)) * 8)];
      }
#pragma unroll
      for (int i = 0; i < 4; ++i)
#pragma unroll
        for (int j = 0; j < 2; ++j)
          acc[i][j] = mfma16(af[i], bfr[j], acc[i][j]);
    }
  }

  float* Cb = outp + (size_t)b * 768 * 2048;
#pragma unroll
  for (int i = 0; i < 4; ++i) {
    int row = m0 + wm + i * 16 + g * 4;
#pragma unroll
    for (int j = 0; j < 2; ++j) {
      int col = n0 + wn + j * 16 + lo;
#pragma unroll
      for (int r2 = 0; r2 < 4; ++r2)
        Cb[(size_t)(row + r2) * 2048 + col] = acc[i][j][r2];
    }
  }
}

// ---------------------------------------------------------------- attention
// Round-10: tile loop unrolled by 2 so the double-buffer index is COMPILE-TIME
// -> all swizzled LDS addresses + staging addresses become loop-invariant
// (hoistable); staging uses pointer-bump. Math identical to round 9:
// bias-as-C-init, T13 defer-max, packed cvt_pkrtz, KVBLK=64, 1 barrier/tile.
__global__ __launch_bounds__(256, 3)
void attn_kernel(const f16* __restrict__ qkt, const f16* __restrict__ vbuf,
                 const int* __restrict__ mask, f16* __restrict__ ctxt) {
  const int bh = blockIdx.y;
  const int b = bh / 12, h = bh % 12;
  const int n0 = blockIdx.x * 128;
  const int t = threadIdx.x;
  const int lane = t & 63, w = t >> 6, g = lane >> 4, lo = lane & 15;

  __shared__ __attribute__((aligned(16))) f16 Kd[2][4096];  // [64 m][64 d] swz
  __shared__ __attribute__((aligned(16))) f16 Vd[2][4096];  // [64 d][64 m] swz
  __shared__ __attribute__((aligned(16))) f16 Ps[4][2048];  // per-wave [32 q][64 m] swz
  __shared__ __attribute__((aligned(16))) f16 bias_s[2048];

  const f16* qb = qkt + (size_t)b * 2048 * 1536;
  const int* mb = mask + b * 2048;
#pragma unroll
  for (int r = 0; r < 8; ++r) {
    int i = r * 256 + t;
    bias_s[i] = (f16)(mb[i] ? 0.f : -60000.f);
  }

  // Q fragments from global; fold 0.125 * log2(e) so exp() -> v_exp_f32.
  constexpr float QS = 0.125f * 1.44269504088896f;
  f16x8 qa[2][2];
#pragma unroll
  for (int fm = 0; fm < 2; ++fm)
#pragma unroll
    for (int kk = 0; kk < 2; ++kk) {
      f16x8 v = *(const f16x8*)&qb[(size_t)(n0 + w * 32 + fm * 16 + lo) * 1536 +
                                   h * 64 + kk * 32 + g * 8];
#pragma unroll
      for (int e = 0; e < 8; ++e) v[e] = (f16)((float)v[e] * QS);
      qa[fm][kk] = v;
    }

  const f32x4 zf = {0.f, 0.f, 0.f, 0.f};
  f32x4 oacc[2][4];
  float mrun[2], lrun[2];
#pragma unroll
  for (int fm = 0; fm < 2; ++fm) {
#pragma unroll
    for (int fd = 0; fd < 4; ++fd) oacc[fm][fd] = zf;
    mrun[fm] = -3e38f;
    lrun[fm] = 0.f;
  }

  const f16* kb_g = qb + 768 + h * 64;
  const f16* vb_g = vbuf + (size_t)b * 768 * 2048 + (size_t)(h * 64) * 2048;
  f16* psw = &Ps[w][0];  // [32 q][64 m], chunk(8xf16)-swizzled c ^= q&7

  // stage one 64-key tile from KP (K rows) / VP (V rows) into buffer BUF
#define STAGE_KV(BUF, KP, VP)                                                 \
  {                                                                           \
    _Pragma("unroll") for (int r = 0; r < 2; ++r) {                           \
      int chunk = r * 256 + t;                                                \
      int row = chunk >> 3;                                                   \
      int c8 = (chunk & 7) ^ (row & 7);                                       \
      gload16((KP) + (size_t)row * 1536 + c8 * 8, &Kd[BUF][0] + chunk * 8);   \
    }                                                                         \
    _Pragma("unroll") for (int r = 0; r < 2; ++r) {                           \
      int chunk = r * 256 + t;                                                \
      int d = chunk >> 3;                                                     \
      int c8 = (chunk & 7) ^ (d & 7);                                         \
      gload16((VP) + (size_t)d * 2048 + c8 * 8, &Vd[BUF][0] + chunk * 8);     \
    }                                                                         \
  }

  // one K/V tile: S^T = K Q^T + bias, online softmax (defer-max), O^T += V P^T
  auto tile_body = [&](const f16* __restrict__ Kb, const f16* __restrict__ Vb,
                       int m0) {
    f32x4 sacc[2][4];
#pragma unroll
    for (int fn = 0; fn < 4; ++fn) {
      f16x4 b4 = *(const f16x4*)&bias_s[m0 + fn * 16 + g * 4];
      f32x4 ba = {(float)b4[0], (float)b4[1], (float)b4[2], (float)b4[3]};
      sacc[0][fn] = ba;
      sacc[1][fn] = ba;
    }
#pragma unroll
    for (int kk = 0; kk < 2; ++kk)
#pragma unroll
      for (int fn = 0; fn < 4; ++fn) {
        int m = fn * 16 + lo;
        f16x8 kf = *(const f16x8*)&Kb[m * 64 + (((kk * 4 + g) ^ (m & 7)) * 8)];
        sacc[0][fn] = mfma16(kf, qa[0][kk], sacc[0][fn]);
        sacc[1][fn] = mfma16(kf, qa[1][kk], sacc[1][fn]);
      }

    f16x4 p16[2][4];
#pragma unroll
    for (int fm = 0; fm < 2; ++fm) {
      f32x4 vm = sacc[fm][0];
#pragma unroll
      for (int fn = 1; fn < 4; ++fn)
#pragma unroll
        for (int r = 0; r < 4; ++r) vm[r] = fmaxf(vm[r], sacc[fm][fn][r]);
      float mx = fmaxf(fmaxf(vm[0], vm[1]), fmaxf(vm[2], vm[3]));
      mx = fmaxf(mx, __shfl_xor(mx, 16, 64));
      mx = fmaxf(mx, __shfl_xor(mx, 32, 64));
      if (__any(mx > mrun[fm] + 8.f)) {  // wave-uniform rescale gate (T13)
        float mnew = fmaxf(mrun[fm], mx);
        float alpha = __builtin_amdgcn_exp2f(mrun[fm] - mnew);
        mrun[fm] = mnew;
        lrun[fm] *= alpha;
#pragma unroll
        for (int fd = 0; fd < 4; ++fd) oacc[fm][fd] *= alpha;
      }
      float mcur = mrun[fm];
      f32x4 vs_ = zf;
#pragma unroll
      for (int fn = 0; fn < 4; ++fn) {
        f32x4 pv;
#pragma unroll
        for (int r = 0; r < 4; ++r)
          pv[r] = __builtin_amdgcn_exp2f(sacc[fm][fn][r] - mcur);
        vs_ += pv;
        f16x2 plo = cvt_pk(pv[0], pv[1]);
        f16x2 phi = cvt_pk(pv[2], pv[3]);
        f16x4 ph = {plo[0], plo[1], phi[0], phi[1]};
        p16[fm][fn] = ph;
      }
      float rs = (vs_[0] + vs_[1]) + (vs_[2] + vs_[3]);
      rs += __shfl_xor(rs, 16, 64);
      rs += __shfl_xor(rs, 32, 64);
      lrun[fm] += rs;
    }

    // P -> per-wave LDS (write pos: chunk fn*2+(g>>1), off (g&1)*4 == m=4g+r)
#pragma unroll
    for (int fm = 0; fm < 2; ++fm) {
      int q32 = fm * 16 + lo;
      int sw = q32 & 7;
#pragma unroll
      for (int fn = 0; fn < 4; ++fn) {
        int cq = fn * 2 + (g >> 1);
        *(f16x4*)&psw[q32 * 64 + ((cq ^ sw) * 8) + (g & 1) * 4] = p16[fm][fn];
      }
    }
    // within-wave DS ops stay ordered; no barrier needed
#pragma unroll
    for (int kk = 0; kk < 2; ++kk) {
      f16x8 pa[2], vf[4];
#pragma unroll
      for (int fm = 0; fm < 2; ++fm) {
        int q32 = fm * 16 + lo;
        pa[fm] =
            *(const f16x8*)&psw[q32 * 64 + (((kk * 4 + g) ^ (q32 & 7)) * 8)];
      }
#pragma unroll
      for (int fd = 0; fd < 4; ++fd) {
        int d = fd * 16 + lo;
        vf[fd] = *(const f16x8*)&Vb[d * 64 + (((kk * 4 + g) ^ (d & 7)) * 8)];
      }
#pragma unroll
      for (int fm = 0; fm < 2; ++fm)
#pragma unroll
        for (int fd = 0; fd < 4; ++fd)
          oacc[fm][fd] = mfma16(vf[fd], pa[fm], oacc[fm][fd]);
    }
  };

  STAGE_KV(0, kb_g, vb_g);
  const f16* kn = kb_g + 64 * 1536;
  const f16* vn = vb_g + 64;
  __syncthreads();  // drains prologue stage + bias writes

#pragma unroll 1
  for (int mt2 = 0; mt2 < 16; ++mt2) {
    // half A: compute buf0 (tile 2*mt2), prefetch tile 2*mt2+1 -> buf1
    STAGE_KV(1, kn, vn);
    kn += 64 * 1536;
    vn += 64;
    tile_body(&Kd[0][0], &Vd[0][0], mt2 * 128);
    __syncthreads();
    // half B: compute buf1 (tile 2*mt2+1), prefetch tile 2*mt2+2 -> buf0
    if (mt2 < 15) {
      STAGE_KV(0, kn, vn);
      kn += 64 * 1536;
      vn += 64;
    }
    tile_body(&Kd[1][0], &Vd[1][0], mt2 * 128 + 64);
    __syncthreads();
  }

  // epilogue: O /= l; oacc quads are d-contiguous -> f16x4 LDS writes
  f16* T2 = &Kd[0][0];  // [128 q][64 d] swz (chunk ^ q&7), overlays Kd+Vd
#pragma unroll
  for (int fm = 0; fm < 2; ++fm) {
    float rcp = 1.f / lrun[fm];
    int q = w * 32 + fm * 16 + lo;
    int sw = q & 7;
#pragma unroll
    for (int fd = 0; fd < 4; ++fd) {
      int c8 = fd * 2 + (g >> 1);
      f16x4 o4 = {(f16)(oacc[fm][fd][0] * rcp), (f16)(oacc[fm][fd][1] * rcp),
                  (f16)(oacc[fm][fd][2] * rcp), (f16)(oacc[fm][fd][3] * rcp)};
      *(f16x4*)&T2[q * 64 + ((c8 ^ sw) * 8) + (g & 1) * 4] = o4;
    }
  }
  __syncthreads();
  f16* cb = ctxt + (size_t)b * 2048 * 768;
  int qrow = t >> 1, half = t & 1;
#pragma unroll
  for (int c = 0; c < 4; ++c) {
    int c8 = half * 4 + c;
    f16x8 v = *(const f16x8*)&T2[qrow * 64 + ((c8 ^ (qrow & 7)) * 8)];
    *(f16x8*)&cb[(size_t)(n0 + qrow) * 768 + h * 64 + c8 * 8] = v;
  }
#undef STAGE_KV
}

// ---------------------------------------------------------------- launch
// ws total = 27,525,120 f16 = 52.5 MiB. Ctxt aliases Xt (dead after GEMM1).
extern "C" void kernel_launch(void* const* d_in, const int* in_sizes, int n_in,
                              void* d_out, int out_size, void* d_ws,
                              size_t ws_size, hipStream_t stream) {
  const float* x  = (const float*)d_in[0];
  const float* Wq = (const float*)d_in[1];
  const float* Wk = (const float*)d_in[2];
  const float* Wv = (const float*)d_in[3];
  const float* Wo = (const float*)d_in[4];
  const int* mask = (const int*)d_in[5];
  float* out = (float*)d_out;

  f16* Xt   = (f16*)d_ws;            // 6291456  (B,2048,768) -- reused as Ctxt
  f16* Wcat = Xt + 6291456;          // 1769472  (2304,768)  Wq|Wk|Wv rows
  f16* Wob  = Wcat + 1769472;        // 589824   (768,768)
  f16* QKt  = Wob + 589824;          // 12582912 (B,2048,1536)
  f16* Vbuf = QKt + 12582912;        // 6291456  (B,768,2048)
  f16* Ctxt = Xt;                    // alias    (B,2048,768)

  convert_w<<<2304, 256, 0, stream>>>(Wq, Wk, Wv, Wo, Wcat, Wob);
  transpose_x<<<dim3(32, 12, 4), 256, 0, stream>>>(x, Xt);
  gemm_kernel<<<dim3(16, 18, 4), 256, 0, stream>>>(Wcat, Xt, QKt, Vbuf);
  attn_kernel<<<dim3(16, 48), 256, 0, stream>>>(QKt, Vbuf, mask, Ctxt);
  gemm_out<<<dim3(32, 6, 4), 256, 0, stream>>>(Wob, Ctxt, out);
}

// Round 12
// 233.834 us; speedup vs baseline: 1.0088x; 1.0088x over previous
//
#include <hip/hip_runtime.h>

typedef _Float16 f16;
typedef __attribute__((ext_vector_type(8))) _Float16 f16x8;
typedef __attribute__((ext_vector_type(4))) _Float16 f16x4;
typedef __attribute__((ext_vector_type(2))) _Float16 f16x2;
typedef __attribute__((ext_vector_type(4))) float f32x4;

#define DEVINL __device__ __forceinline__

DEVINL void gload16(const void* g, void* l) {
  __builtin_amdgcn_global_load_lds(
      (const __attribute__((address_space(1))) void*)g,
      (__attribute__((address_space(3))) void*)l, 16, 0, 0);
}

DEVINL f32x4 mfma16(f16x8 a, f16x8 b, f32x4 c) {
  return __builtin_amdgcn_mfma_f32_16x16x32_f16(a, b, c, 0, 0, 0);
}

// packed f32x2 -> f16x2 (RTZ); builtin returns __fp16x2, bit-identical layout
DEVINL f16x2 cvt_pk(float a, float b) {
  return __builtin_bit_cast(f16x2, __builtin_amdgcn_cvt_pkrtz(a, b));
}

// ---------------------------------------------------------------- converts
// One launch for Wq|Wk|Wv -> Wcat and Wo -> Wob (4 x 589824 f32 -> f16).
__global__ __launch_bounds__(256) void convert_w(const float* __restrict__ wq,
                                                 const float* __restrict__ wk,
                                                 const float* __restrict__ wv,
                                                 const float* __restrict__ wo,
                                                 f16* __restrict__ wcat,
                                                 f16* __restrict__ wob) {
  int seg = blockIdx.x / 576;
  int i = ((blockIdx.x % 576) * 256 + threadIdx.x) * 4;
  const float* src = seg == 0 ? wq : (seg == 1 ? wk : (seg == 2 ? wv : wo));
  f16* dst = seg < 3 ? wcat + seg * 589824 : wob;
  f32x4 v = *(const f32x4*)(src + i);
  f16x4 o = {(f16)v[0], (f16)v[1], (f16)v[2], (f16)v[3]};
  *(f16x4*)(dst + i) = o;
}

// x (B,768,2048) f32 -> Xt (B,2048,768) f16   (64x64 tiles via padded LDS)
__global__ __launch_bounds__(256) void transpose_x(const float* __restrict__ x,
                                                   f16* __restrict__ xt) {
  __shared__ __attribute__((aligned(16))) f16 T[64 * 66];
  const int b = blockIdx.z, c0 = blockIdx.y * 64, n0 = blockIdx.x * 64;
  const int t = threadIdx.x;
  const float* xb = x + (size_t)b * 768 * 2048;
#pragma unroll
  for (int r = 0; r < 4; ++r) {
    int chunk = r * 256 + t;
    int row = chunk >> 4, c4 = (chunk & 15) * 4;
    f32x4 v = *(const f32x4*)&xb[(size_t)(c0 + row) * 2048 + n0 + c4];
#pragma unroll
    for (int e = 0; e < 4; ++e) T[row * 66 + c4 + e] = (f16)v[e];
  }
  __syncthreads();
  f16* xtb = xt + (size_t)b * 2048 * 768;
  int n = t >> 2, cp = (t & 3) * 16;
  __attribute__((aligned(16))) f16 vals[16];
#pragma unroll
  for (int j = 0; j < 16; ++j) vals[j] = T[(cp + j) * 66 + n];
  *(f16x8*)&xtb[(size_t)(n0 + n) * 768 + c0 + cp] = *(const f16x8*)&vals[0];
  *(f16x8*)&xtb[(size_t)(n0 + n) * 768 + c0 + cp + 8] = *(const f16x8*)&vals[8];
}

// ---------------------------------------------------------------- GEMM
// C[m0+128][n0+128] = A(M,768) @ Bt(2048,768)^T   per batch z.
// kind==1: fp32 direct store to outp (B,768,2048)    [round-9 proven config]
// kind==0: m0<1536 -> transposed f16 store into qkt (B,2048,1536)
//          m0>=1536 -> direct f16 store into vbuf (B,768,2048)
__global__ __launch_bounds__(256, 2)
void gemm_kernel(const f16* __restrict__ A, const f16* __restrict__ Bt,
                 f16* __restrict__ qkt, f16* __restrict__ vbuf,
                 float* __restrict__ outp, int kind) {
  constexpr int K = 768;
  const int b = blockIdx.z;
  const int n0 = blockIdx.x * 128;
  const int m0 = blockIdx.y * 128;
  const int t = threadIdx.x;
  const int lane = t & 63, w = t >> 6, g = lane >> 4, lo = lane & 15;
  const int wm = (w >> 1) * 64, wn = (w & 1) * 64;

  __shared__ __attribute__((aligned(16))) f16 smem[16384];
  f16* As = smem;          // [128 m][64 k], chunk-swizzled (c8 ^= row&7)
  f16* Bs = smem + 8192;   // [128 n][64 k], same swizzle

  const f16* Ab = A + (size_t)m0 * K;
  const f16* Bb = Bt + (size_t)b * 2048 * K + (size_t)n0 * K;

  const f32x4 zf = {0.f, 0.f, 0.f, 0.f};
  f32x4 acc[4][4];
#pragma unroll
  for (int i = 0; i < 4; ++i)
#pragma unroll
    for (int j = 0; j < 4; ++j) acc[i][j] = zf;

  for (int kt = 0; kt < K; kt += 64) {
    __syncthreads();
#pragma unroll
    for (int r = 0; r < 4; ++r) {
      int chunk = r * 256 + t;
      int row = chunk >> 3;
      int c8 = (chunk & 7) ^ (row & 7);
      gload16(Ab + (size_t)row * K + kt + c8 * 8, As + chunk * 8);
    }
#pragma unroll
    for (int r = 0; r < 4; ++r) {
      int chunk = r * 256 + t;
      int row = chunk >> 3;
      int c8 = (chunk & 7) ^ (row & 7);
      gload16(Bb + (size_t)row * K + kt + c8 * 8, Bs + chunk * 8);
    }
    __syncthreads();
#pragma unroll
    for (int kk = 0; kk < 2; ++kk) {
      f16x8 af[4], bfr[4];
#pragma unroll
      for (int i = 0; i < 4; ++i) {
        int row = wm + i * 16 + lo;
        af[i] = *(const f16x8*)&As[row * 64 + (((kk * 4 + g) ^ (row & 7)) * 8)];
      }
#pragma unroll
      for (int j = 0; j < 4; ++j) {
        int col = wn + j * 16 + lo;
        bfr[j] = *(const f16x8*)&Bs[col * 64 + (((kk * 4 + g) ^ (col & 7)) * 8)];
      }
#pragma unroll
      for (int i = 0; i < 4; ++i)
#pragma unroll
        for (int j = 0; j < 4; ++j)
          acc[i][j] = mfma16(af[i], bfr[j], acc[i][j]);
    }
  }

  if (kind == 1) {
    float* Cb = outp + (size_t)b * 768 * 2048;
#pragma unroll
    for (int i = 0; i < 4; ++i) {
      int row = m0 + wm + i * 16 + g * 4;
#pragma unroll
      for (int j = 0; j < 4; ++j) {
        int col = n0 + wn + j * 16 + lo;
#pragma unroll
        for (int r2 = 0; r2 < 4; ++r2)
          Cb[(size_t)(row + r2) * 2048 + col] = acc[i][j][r2];
      }
    }
  } else if (m0 >= 1536) {
    f16* Vb = vbuf + (size_t)b * 768 * 2048;
#pragma unroll
    for (int i = 0; i < 4; ++i) {
      int row = m0 - 1536 + wm + i * 16 + g * 4;
#pragma unroll
      for (int j = 0; j < 4; ++j) {
        int col = n0 + wn + j * 16 + lo;
#pragma unroll
        for (int r2 = 0; r2 < 4; ++r2)
          Vb[(size_t)(row + r2) * 2048 + col] = (f16)acc[i][j][r2];
      }
    }
  } else {
    // transpose-store via LDS: QKt[b][n0+n][m0 + m] = C[m][n]
    __syncthreads();
    f16* T = smem;  // [128 n][128 m], chunk16-swizzled (c ^= n&15)
#pragma unroll
    for (int i = 0; i < 4; ++i)
#pragma unroll
      for (int j = 0; j < 4; ++j) {
        int nl = wn + j * 16 + lo;
#pragma unroll
        for (int r2 = 0; r2 < 4; ++r2) {
          int ml = wm + i * 16 + g * 4 + r2;
          T[nl * 128 + (((ml >> 3) ^ (nl & 15)) * 8) + (ml & 7)] =
              (f16)acc[i][j][r2];
        }
      }
    __syncthreads();
    f16* Qb = qkt + (size_t)b * 2048 * 1536;
    int n = t >> 1, half = t & 1;
#pragma unroll
    for (int c = 0; c < 8; ++c) {
      int chunk = half * 8 + c;
      f16x8 v = *(const f16x8*)&T[n * 128 + ((chunk ^ (n & 15)) * 8)];
      *(f16x8*)&Qb[(size_t)(n0 + n) * 1536 + m0 + chunk * 8] = v;
    }
  }
}

// ---------------------------------------------------------------- attention
// Round-12 resubmit of round-11 (broker failed; kernel never ran):
// round-10 structure (unroll-by-2 dbuf, bias-as-C-init, T13 defer-max,
// packed cvt) + T5 s_setprio(1) around both MFMA clusters.
// Mechanism: 2-3 independent blocks/CU run phase-shifted (barriers are
// per-block) -> CU scheduler can prefer MFMA-issuing waves (m191 regime).
__global__ __launch_bounds__(256, 3)
void attn_kernel(const f16* __restrict__ qkt, const f16* __restrict__ vbuf,
                 const int* __restrict__ mask, f16* __restrict__ ctxt) {
  const int bh = blockIdx.y;
  const int b = bh / 12, h = bh % 12;
  const int n0 = blockIdx.x * 128;
  const int t = threadIdx.x;
  const int lane = t & 63, w = t >> 6, g = lane >> 4, lo = lane & 15;

  __shared__ __attribute__((aligned(16))) f16 Kd[2][4096];  // [64 m][64 d] swz
  __shared__ __attribute__((aligned(16))) f16 Vd[2][4096];  // [64 d][64 m] swz
  __shared__ __attribute__((aligned(16))) f16 Ps[4][2048];  // per-wave [32 q][64 m] swz
  __shared__ __attribute__((aligned(16))) f16 bias_s[2048];

  const f16* qb = qkt + (size_t)b * 2048 * 1536;
  const int* mb = mask + b * 2048;
#pragma unroll
  for (int r = 0; r < 8; ++r) {
    int i = r * 256 + t;
    bias_s[i] = (f16)(mb[i] ? 0.f : -60000.f);
  }

  // Q fragments from global; fold 0.125 * log2(e) so exp() -> v_exp_f32.
  constexpr float QS = 0.125f * 1.44269504088896f;
  f16x8 qa[2][2];
#pragma unroll
  for (int fm = 0; fm < 2; ++fm)
#pragma unroll
    for (int kk = 0; kk < 2; ++kk) {
      f16x8 v = *(const f16x8*)&qb[(size_t)(n0 + w * 32 + fm * 16 + lo) * 1536 +
                                   h * 64 + kk * 32 + g * 8];
#pragma unroll
      for (int e = 0; e < 8; ++e) v[e] = (f16)((float)v[e] * QS);
      qa[fm][kk] = v;
    }

  const f32x4 zf = {0.f, 0.f, 0.f, 0.f};
  f32x4 oacc[2][4];
  float mrun[2], lrun[2];
#pragma unroll
  for (int fm = 0; fm < 2; ++fm) {
#pragma unroll
    for (int fd = 0; fd < 4; ++fd) oacc[fm][fd] = zf;
    mrun[fm] = -3e38f;
    lrun[fm] = 0.f;
  }

  const f16* kb_g = qb + 768 + h * 64;
  const f16* vb_g = vbuf + (size_t)b * 768 * 2048 + (size_t)(h * 64) * 2048;
  f16* psw = &Ps[w][0];  // [32 q][64 m], chunk(8xf16)-swizzled c ^= q&7

  // stage one 64-key tile from KP (K rows) / VP (V rows) into buffer BUF
#define STAGE_KV(BUF, KP, VP)                                                 \
  {                                                                           \
    _Pragma("unroll") for (int r = 0; r < 2; ++r) {                           \
      int chunk = r * 256 + t;                                                \
      int row = chunk >> 3;                                                   \
      int c8 = (chunk & 7) ^ (row & 7);                                       \
      gload16((KP) + (size_t)row * 1536 + c8 * 8, &Kd[BUF][0] + chunk * 8);   \
    }                                                                         \
    _Pragma("unroll") for (int r = 0; r < 2; ++r) {                           \
      int chunk = r * 256 + t;                                                \
      int d = chunk >> 3;                                                     \
      int c8 = (chunk & 7) ^ (d & 7);                                         \
      gload16((VP) + (size_t)d * 2048 + c8 * 8, &Vd[BUF][0] + chunk * 8);     \
    }                                                                         \
  }

  // one K/V tile: S^T = K Q^T + bias, online softmax (defer-max), O^T += V P^T
  auto tile_body = [&](const f16* __restrict__ Kb, const f16* __restrict__ Vb,
                       int m0) {
    f32x4 sacc[2][4];
#pragma unroll
    for (int fn = 0; fn < 4; ++fn) {
      f16x4 b4 = *(const f16x4*)&bias_s[m0 + fn * 16 + g * 4];
      f32x4 ba = {(float)b4[0], (float)b4[1], (float)b4[2], (float)b4[3]};
      sacc[0][fn] = ba;
      sacc[1][fn] = ba;
    }
    __builtin_amdgcn_s_setprio(1);  // T5: favor this wave through QK^T MFMAs
#pragma unroll
    for (int kk = 0; kk < 2; ++kk)
#pragma unroll
      for (int fn = 0; fn < 4; ++fn) {
        int m = fn * 16 + lo;
        f16x8 kf = *(const f16x8*)&Kb[m * 64 + (((kk * 4 + g) ^ (m & 7)) * 8)];
        sacc[0][fn] = mfma16(kf, qa[0][kk], sacc[0][fn]);
        sacc[1][fn] = mfma16(kf, qa[1][kk], sacc[1][fn]);
      }
    __builtin_amdgcn_s_setprio(0);

    f16x4 p16[2][4];
#pragma unroll
    for (int fm = 0; fm < 2; ++fm) {
      f32x4 vm = sacc[fm][0];
#pragma unroll
      for (int fn = 1; fn < 4; ++fn)
#pragma unroll
        for (int r = 0; r < 4; ++r) vm[r] = fmaxf(vm[r], sacc[fm][fn][r]);
      float mx = fmaxf(fmaxf(vm[0], vm[1]), fmaxf(vm[2], vm[3]));
      mx = fmaxf(mx, __shfl_xor(mx, 16, 64));
      mx = fmaxf(mx, __shfl_xor(mx, 32, 64));
      if (__any(mx > mrun[fm] + 8.f)) {  // wave-uniform rescale gate (T13)
        float mnew = fmaxf(mrun[fm], mx);
        float alpha = __builtin_amdgcn_exp2f(mrun[fm] - mnew);
        mrun[fm] = mnew;
        lrun[fm] *= alpha;
#pragma unroll
        for (int fd = 0; fd < 4; ++fd) oacc[fm][fd] *= alpha;
      }
      float mcur = mrun[fm];
      f32x4 vs_ = zf;
#pragma unroll
      for (int fn = 0; fn < 4; ++fn) {
        f32x4 pv;
#pragma unroll
        for (int r = 0; r < 4; ++r)
          pv[r] = __builtin_amdgcn_exp2f(sacc[fm][fn][r] - mcur);
        vs_ += pv;
        f16x2 plo = cvt_pk(pv[0], pv[1]);
        f16x2 phi = cvt_pk(pv[2], pv[3]);
        f16x4 ph = {plo[0], plo[1], phi[0], phi[1]};
        p16[fm][fn] = ph;
      }
      float rs = (vs_[0] + vs_[1]) + (vs_[2] + vs_[3]);
      rs += __shfl_xor(rs, 16, 64);
      rs += __shfl_xor(rs, 32, 64);
      lrun[fm] += rs;
    }

    // P -> per-wave LDS (write pos: chunk fn*2+(g>>1), off (g&1)*4 == m=4g+r)
#pragma unroll
    for (int fm = 0; fm < 2; ++fm) {
      int q32 = fm * 16 + lo;
      int sw = q32 & 7;
#pragma unroll
      for (int fn = 0; fn < 4; ++fn) {
        int cq = fn * 2 + (g >> 1);
        *(f16x4*)&psw[q32 * 64 + ((cq ^ sw) * 8) + (g & 1) * 4] = p16[fm][fn];
      }
    }
    // within-wave DS ops stay ordered; no barrier needed
    __builtin_amdgcn_s_setprio(1);  // T5: favor PV MFMA cluster
#pragma unroll
    for (int kk = 0; kk < 2; ++kk) {
      f16x8 pa[2], vf[4];
#pragma unroll
      for (int fm = 0; fm < 2; ++fm) {
        int q32 = fm * 16 + lo;
        pa[fm] =
            *(const f16x8*)&psw[q32 * 64 + (((kk * 4 + g) ^ (q32 & 7)) * 8)];
      }
#pragma unroll
      for (int fd = 0; fd < 4; ++fd) {
        int d = fd * 16 + lo;
        vf[fd] = *(const f16x8*)&Vb[d * 64 + (((kk * 4 + g) ^ (d & 7)) * 8)];
      }
#pragma unroll
      for (int fm = 0; fm < 2; ++fm)
#pragma unroll
        for (int fd = 0; fd < 4; ++fd)
          oacc[fm][fd] = mfma16(vf[fd], pa[fm], oacc[fm][fd]);
    }
    __builtin_amdgcn_s_setprio(0);
  };

  STAGE_KV(0, kb_g, vb_g);
  const f16* kn = kb_g + 64 * 1536;
  const f16* vn = vb_g + 64;
  __syncthreads();  // drains prologue stage + bias writes

#pragma unroll 1
  for (int mt2 = 0; mt2 < 16; ++mt2) {
    // half A: compute buf0 (tile 2*mt2), prefetch tile 2*mt2+1 -> buf1
    STAGE_KV(1, kn, vn);
    kn += 64 * 1536;
    vn += 64;
    tile_body(&Kd[0][0], &Vd[0][0], mt2 * 128);
    __syncthreads();
    // half B: compute buf1 (tile 2*mt2+1), prefetch tile 2*mt2+2 -> buf0
    if (mt2 < 15) {
      STAGE_KV(0, kn, vn);
      kn += 64 * 1536;
      vn += 64;
    }
    tile_body(&Kd[1][0], &Vd[1][0], mt2 * 128 + 64);
    __syncthreads();
  }

  // epilogue: O /= l; oacc quads are d-contiguous -> f16x4 LDS writes
  f16* T2 = &Kd[0][0];  // [128 q][64 d] swz (chunk ^ q&7), overlays Kd+Vd
#pragma unroll
  for (int fm = 0; fm < 2; ++fm) {
    float rcp = 1.f / lrun[fm];
    int q = w * 32 + fm * 16 + lo;
    int sw = q & 7;
#pragma unroll
    for (int fd = 0; fd < 4; ++fd) {
      int c8 = fd * 2 + (g >> 1);
      f16x4 o4 = {(f16)(oacc[fm][fd][0] * rcp), (f16)(oacc[fm][fd][1] * rcp),
                  (f16)(oacc[fm][fd][2] * rcp), (f16)(oacc[fm][fd][3] * rcp)};
      *(f16x4*)&T2[q * 64 + ((c8 ^ sw) * 8) + (g & 1) * 4] = o4;
    }
  }
  __syncthreads();
  f16* cb = ctxt + (size_t)b * 2048 * 768;
  int qrow = t >> 1, half = t & 1;
#pragma unroll
  for (int c = 0; c < 4; ++c) {
    int c8 = half * 4 + c;
    f16x8 v = *(const f16x8*)&T2[qrow * 64 + ((c8 ^ (qrow & 7)) * 8)];
    *(f16x8*)&cb[(size_t)(n0 + qrow) * 768 + h * 64 + c8 * 8] = v;
  }
#undef STAGE_KV
}

// ---------------------------------------------------------------- launch
// ws total = 27,525,120 f16 = 52.5 MiB. Ctxt aliases Xt (dead after GEMM1).
extern "C" void kernel_launch(void* const* d_in, const int* in_sizes, int n_in,
                              void* d_out, int out_size, void* d_ws,
                              size_t ws_size, hipStream_t stream) {
  const float* x  = (const float*)d_in[0];
  const float* Wq = (const float*)d_in[1];
  const float* Wk = (const float*)d_in[2];
  const float* Wv = (const float*)d_in[3];
  const float* Wo = (const float*)d_in[4];
  const int* mask = (const int*)d_in[5];
  float* out = (float*)d_out;

  f16* Xt   = (f16*)d_ws;            // 6291456  (B,2048,768) -- reused as Ctxt
  f16* Wcat = Xt + 6291456;          // 1769472  (2304,768)  Wq|Wk|Wv rows
  f16* Wob  = Wcat + 1769472;        // 589824   (768,768)
  f16* QKt  = Wob + 589824;          // 12582912 (B,2048,1536)
  f16* Vbuf = QKt + 12582912;        // 6291456  (B,768,2048)
  f16* Ctxt = Xt;                    // alias    (B,2048,768)

  convert_w<<<2304, 256, 0, stream>>>(Wq, Wk, Wv, Wo, Wcat, Wob);
  transpose_x<<<dim3(32, 12, 4), 256, 0, stream>>>(x, Xt);
  gemm_kernel<<<dim3(16, 18, 4), 256, 0, stream>>>(Wcat, Xt, QKt, Vbuf, nullptr, 0);
  attn_kernel<<<dim3(16, 48), 256, 0, stream>>>(QKt, Vbuf, mask, Ctxt);
  gemm_kernel<<<dim3(16, 6, 4), 256, 0, stream>>>(Wob, Ctxt, nullptr, nullptr, out, 1);
}

// Round 13
// 226.546 us; speedup vs baseline: 1.0412x; 1.0322x over previous
//
#include <hip/hip_runtime.h>

typedef _Float16 f16;
typedef __attribute__((ext_vector_type(8))) _Float16 f16x8;
typedef __attribute__((ext_vector_type(4))) _Float16 f16x4;
typedef __attribute__((ext_vector_type(2))) _Float16 f16x2;
typedef __attribute__((ext_vector_type(4))) float f32x4;

#define DEVINL __device__ __forceinline__

DEVINL void gload16(const void* g, void* l) {
  __builtin_amdgcn_global_load_lds(
      (const __attribute__((address_space(1))) void*)g,
      (__attribute__((address_space(3))) void*)l, 16, 0, 0);
}

DEVINL f32x4 mfma16(f16x8 a, f16x8 b, f32x4 c) {
  return __builtin_amdgcn_mfma_f32_16x16x32_f16(a, b, c, 0, 0, 0);
}

// packed f32x2 -> f16x2 (RTZ); builtin returns __fp16x2, bit-identical layout
DEVINL f16x2 cvt_pk(float a, float b) {
  return __builtin_bit_cast(f16x2, __builtin_amdgcn_cvt_pkrtz(a, b));
}

// ---------------------------------------------------------------- converts
// One launch for Wq|Wk|Wv -> Wcat and Wo -> Wob (4 x 589824 f32 -> f16).
__global__ __launch_bounds__(256) void convert_w(const float* __restrict__ wq,
                                                 const float* __restrict__ wk,
                                                 const float* __restrict__ wv,
                                                 const float* __restrict__ wo,
                                                 f16* __restrict__ wcat,
                                                 f16* __restrict__ wob) {
  int seg = blockIdx.x / 576;
  int i = ((blockIdx.x % 576) * 256 + threadIdx.x) * 4;
  const float* src = seg == 0 ? wq : (seg == 1 ? wk : (seg == 2 ? wv : wo));
  f16* dst = seg < 3 ? wcat + seg * 589824 : wob;
  f32x4 v = *(const f32x4*)(src + i);
  f16x4 o = {(f16)v[0], (f16)v[1], (f16)v[2], (f16)v[3]};
  *(f16x4*)(dst + i) = o;
}

// x (B,768,2048) f32 -> Xt (B,2048,768) f16   (64x64 tiles via padded LDS)
__global__ __launch_bounds__(256) void transpose_x(const float* __restrict__ x,
                                                   f16* __restrict__ xt) {
  __shared__ __attribute__((aligned(16))) f16 T[64 * 66];
  const int b = blockIdx.z, c0 = blockIdx.y * 64, n0 = blockIdx.x * 64;
  const int t = threadIdx.x;
  const float* xb = x + (size_t)b * 768 * 2048;
#pragma unroll
  for (int r = 0; r < 4; ++r) {
    int chunk = r * 256 + t;
    int row = chunk >> 4, c4 = (chunk & 15) * 4;
    f32x4 v = *(const f32x4*)&xb[(size_t)(c0 + row) * 2048 + n0 + c4];
#pragma unroll
    for (int e = 0; e < 4; ++e) T[row * 66 + c4 + e] = (f16)v[e];
  }
  __syncthreads();
  f16* xtb = xt + (size_t)b * 2048 * 768;
  int n = t >> 2, cp = (t & 3) * 16;
  __attribute__((aligned(16))) f16 vals[16];
#pragma unroll
  for (int j = 0; j < 16; ++j) vals[j] = T[(cp + j) * 66 + n];
  *(f16x8*)&xtb[(size_t)(n0 + n) * 768 + c0 + cp] = *(const f16x8*)&vals[0];
  *(f16x8*)&xtb[(size_t)(n0 + n) * 768 + c0 + cp + 8] = *(const f16x8*)&vals[8];
}

// ---------------------------------------------------------------- GEMM
// C[m0+128][n0+128] = A(M,768) @ Bt(2048,768)^T   per batch z.
// kind==1: fp32 direct store to outp (B,768,2048)
// kind==0: m0<1536 -> transposed f16 store into qkt (B,2048,1536)
//          m0>=1536 -> direct f16 store into vbuf (B,768,2048)
// Round-13: __launch_bounds__(256,3) -- LDS 32KB allows 5 blocks/CU; the old
// (256,2) capped occupancy at 2 blocks/CU. m97 evidence: this structure peaks
// at ~3 blocks/CU (implicit wave-level MFMA/staging overlap). GEMM1 grid is
// 4.5 blocks/CU so occupancy binds; GEMM2 is grid-limited (neutral).
__global__ __launch_bounds__(256, 3)
void gemm_kernel(const f16* __restrict__ A, const f16* __restrict__ Bt,
                 f16* __restrict__ qkt, f16* __restrict__ vbuf,
                 float* __restrict__ outp, int kind) {
  constexpr int K = 768;
  const int b = blockIdx.z;
  const int n0 = blockIdx.x * 128;
  const int m0 = blockIdx.y * 128;
  const int t = threadIdx.x;
  const int lane = t & 63, w = t >> 6, g = lane >> 4, lo = lane & 15;
  const int wm = (w >> 1) * 64, wn = (w & 1) * 64;

  __shared__ __attribute__((aligned(16))) f16 smem[16384];
  f16* As = smem;          // [128 m][64 k], chunk-swizzled (c8 ^= row&7)
  f16* Bs = smem + 8192;   // [128 n][64 k], same swizzle

  const f16* Ab = A + (size_t)m0 * K;
  const f16* Bb = Bt + (size_t)b * 2048 * K + (size_t)n0 * K;

  const f32x4 zf = {0.f, 0.f, 0.f, 0.f};
  f32x4 acc[4][4];
#pragma unroll
  for (int i = 0; i < 4; ++i)
#pragma unroll
    for (int j = 0; j < 4; ++j) acc[i][j] = zf;

  for (int kt = 0; kt < K; kt += 64) {
    __syncthreads();
#pragma unroll
    for (int r = 0; r < 4; ++r) {
      int chunk = r * 256 + t;
      int row = chunk >> 3;
      int c8 = (chunk & 7) ^ (row & 7);
      gload16(Ab + (size_t)row * K + kt + c8 * 8, As + chunk * 8);
    }
#pragma unroll
    for (int r = 0; r < 4; ++r) {
      int chunk = r * 256 + t;
      int row = chunk >> 3;
      int c8 = (chunk & 7) ^ (row & 7);
      gload16(Bb + (size_t)row * K + kt + c8 * 8, Bs + chunk * 8);
    }
    __syncthreads();
#pragma unroll
    for (int kk = 0; kk < 2; ++kk) {
      f16x8 af[4], bfr[4];
#pragma unroll
      for (int i = 0; i < 4; ++i) {
        int row = wm + i * 16 + lo;
        af[i] = *(const f16x8*)&As[row * 64 + (((kk * 4 + g) ^ (row & 7)) * 8)];
      }
#pragma unroll
      for (int j = 0; j < 4; ++j) {
        int col = wn + j * 16 + lo;
        bfr[j] = *(const f16x8*)&Bs[col * 64 + (((kk * 4 + g) ^ (col & 7)) * 8)];
      }
#pragma unroll
      for (int i = 0; i < 4; ++i)
#pragma unroll
        for (int j = 0; j < 4; ++j)
          acc[i][j] = mfma16(af[i], bfr[j], acc[i][j]);
    }
  }

  if (kind == 1) {
    float* Cb = outp + (size_t)b * 768 * 2048;
#pragma unroll
    for (int i = 0; i < 4; ++i) {
      int row = m0 + wm + i * 16 + g * 4;
#pragma unroll
      for (int j = 0; j < 4; ++j) {
        int col = n0 + wn + j * 16 + lo;
#pragma unroll
        for (int r2 = 0; r2 < 4; ++r2)
          Cb[(size_t)(row + r2) * 2048 + col] = acc[i][j][r2];
      }
    }
  } else if (m0 >= 1536) {
    f16* Vb = vbuf + (size_t)b * 768 * 2048;
#pragma unroll
    for (int i = 0; i < 4; ++i) {
      int row = m0 - 1536 + wm + i * 16 + g * 4;
#pragma unroll
      for (int j = 0; j < 4; ++j) {
        int col = n0 + wn + j * 16 + lo;
#pragma unroll
        for (int r2 = 0; r2 < 4; ++r2)
          Vb[(size_t)(row + r2) * 2048 + col] = (f16)acc[i][j][r2];
      }
    }
  } else {
    // transpose-store via LDS: QKt[b][n0+n][m0 + m] = C[m][n]
    __syncthreads();
    f16* T = smem;  // [128 n][128 m], chunk16-swizzled (c ^= n&15)
#pragma unroll
    for (int i = 0; i < 4; ++i)
#pragma unroll
      for (int j = 0; j < 4; ++j) {
        int nl = wn + j * 16 + lo;
#pragma unroll
        for (int r2 = 0; r2 < 4; ++r2) {
          int ml = wm + i * 16 + g * 4 + r2;
          T[nl * 128 + (((ml >> 3) ^ (nl & 15)) * 8) + (ml & 7)] =
              (f16)acc[i][j][r2];
        }
      }
    __syncthreads();
    f16* Qb = qkt + (size_t)b * 2048 * 1536;
    int n = t >> 1, half = t & 1;
#pragma unroll
    for (int c = 0; c < 8; ++c) {
      int chunk = half * 8 + c;
      f16x8 v = *(const f16x8*)&T[n * 128 + ((chunk ^ (n & 15)) * 8)];
      *(f16x8*)&Qb[(size_t)(n0 + n) * 1536 + m0 + chunk * 8] = v;
    }
  }
}

// ---------------------------------------------------------------- attention
// Round-13: byte-identical to round 12 (clean A/B; GEMM-only round).
// Structure: unroll-by-2 dbuf KVBLK=64, bias-as-C-init, T13 defer-max,
// packed cvt, T5 setprio (measured null but harmless).
__global__ __launch_bounds__(256, 3)
void attn_kernel(const f16* __restrict__ qkt, const f16* __restrict__ vbuf,
                 const int* __restrict__ mask, f16* __restrict__ ctxt) {
  const int bh = blockIdx.y;
  const int b = bh / 12, h = bh % 12;
  const int n0 = blockIdx.x * 128;
  const int t = threadIdx.x;
  const int lane = t & 63, w = t >> 6, g = lane >> 4, lo = lane & 15;

  __shared__ __attribute__((aligned(16))) f16 Kd[2][4096];  // [64 m][64 d] swz
  __shared__ __attribute__((aligned(16))) f16 Vd[2][4096];  // [64 d][64 m] swz
  __shared__ __attribute__((aligned(16))) f16 Ps[4][2048];  // per-wave [32 q][64 m] swz
  __shared__ __attribute__((aligned(16))) f16 bias_s[2048];

  const f16* qb = qkt + (size_t)b * 2048 * 1536;
  const int* mb = mask + b * 2048;
#pragma unroll
  for (int r = 0; r < 8; ++r) {
    int i = r * 256 + t;
    bias_s[i] = (f16)(mb[i] ? 0.f : -60000.f);
  }

  // Q fragments from global; fold 0.125 * log2(e) so exp() -> v_exp_f32.
  constexpr float QS = 0.125f * 1.44269504088896f;
  f16x8 qa[2][2];
#pragma unroll
  for (int fm = 0; fm < 2; ++fm)
#pragma unroll
    for (int kk = 0; kk < 2; ++kk) {
      f16x8 v = *(const f16x8*)&qb[(size_t)(n0 + w * 32 + fm * 16 + lo) * 1536 +
                                   h * 64 + kk * 32 + g * 8];
#pragma unroll
      for (int e = 0; e < 8; ++e) v[e] = (f16)((float)v[e] * QS);
      qa[fm][kk] = v;
    }

  const f32x4 zf = {0.f, 0.f, 0.f, 0.f};
  f32x4 oacc[2][4];
  float mrun[2], lrun[2];
#pragma unroll
  for (int fm = 0; fm < 2; ++fm) {
#pragma unroll
    for (int fd = 0; fd < 4; ++fd) oacc[fm][fd] = zf;
    mrun[fm] = -3e38f;
    lrun[fm] = 0.f;
  }

  const f16* kb_g = qb + 768 + h * 64;
  const f16* vb_g = vbuf + (size_t)b * 768 * 2048 + (size_t)(h * 64) * 2048;
  f16* psw = &Ps[w][0];  // [32 q][64 m], chunk(8xf16)-swizzled c ^= q&7

  // stage one 64-key tile from KP (K rows) / VP (V rows) into buffer BUF
#define STAGE_KV(BUF, KP, VP)                                                 \
  {                                                                           \
    _Pragma("unroll") for (int r = 0; r < 2; ++r) {                           \
      int chunk = r * 256 + t;                                                \
      int row = chunk >> 3;                                                   \
      int c8 = (chunk & 7) ^ (row & 7);                                       \
      gload16((KP) + (size_t)row * 1536 + c8 * 8, &Kd[BUF][0] + chunk * 8);   \
    }                                                                         \
    _Pragma("unroll") for (int r = 0; r < 2; ++r) {                           \
      int chunk = r * 256 + t;                                                \
      int d = chunk >> 3;                                                     \
      int c8 = (chunk & 7) ^ (d & 7);                                         \
      gload16((VP) + (size_t)d * 2048 + c8 * 8, &Vd[BUF][0] + chunk * 8);     \
    }                                                                         \
  }

  // one K/V tile: S^T = K Q^T + bias, online softmax (defer-max), O^T += V P^T
  auto tile_body = [&](const f16* __restrict__ Kb, const f16* __restrict__ Vb,
                       int m0) {
    f32x4 sacc[2][4];
#pragma unroll
    for (int fn = 0; fn < 4; ++fn) {
      f16x4 b4 = *(const f16x4*)&bias_s[m0 + fn * 16 + g * 4];
      f32x4 ba = {(float)b4[0], (float)b4[1], (float)b4[2], (float)b4[3]};
      sacc[0][fn] = ba;
      sacc[1][fn] = ba;
    }
    __builtin_amdgcn_s_setprio(1);  // T5: favor this wave through QK^T MFMAs
#pragma unroll
    for (int kk = 0; kk < 2; ++kk)
#pragma unroll
      for (int fn = 0; fn < 4; ++fn) {
        int m = fn * 16 + lo;
        f16x8 kf = *(const f16x8*)&Kb[m * 64 + (((kk * 4 + g) ^ (m & 7)) * 8)];
        sacc[0][fn] = mfma16(kf, qa[0][kk], sacc[0][fn]);
        sacc[1][fn] = mfma16(kf, qa[1][kk], sacc[1][fn]);
      }
    __builtin_amdgcn_s_setprio(0);

    f16x4 p16[2][4];
#pragma unroll
    for (int fm = 0; fm < 2; ++fm) {
      f32x4 vm = sacc[fm][0];
#pragma unroll
      for (int fn = 1; fn < 4; ++fn)
#pragma unroll
        for (int r = 0; r < 4; ++r) vm[r] = fmaxf(vm[r], sacc[fm][fn][r]);
      float mx = fmaxf(fmaxf(vm[0], vm[1]), fmaxf(vm[2], vm[3]));
      mx = fmaxf(mx, __shfl_xor(mx, 16, 64));
      mx = fmaxf(mx, __shfl_xor(mx, 32, 64));
      if (__any(mx > mrun[fm] + 8.f)) {  // wave-uniform rescale gate (T13)
        float mnew = fmaxf(mrun[fm], mx);
        float alpha = __builtin_amdgcn_exp2f(mrun[fm] - mnew);
        mrun[fm] = mnew;
        lrun[fm] *= alpha;
#pragma unroll
        for (int fd = 0; fd < 4; ++fd) oacc[fm][fd] *= alpha;
      }
      float mcur = mrun[fm];
      f32x4 vs_ = zf;
#pragma unroll
      for (int fn = 0; fn < 4; ++fn) {
        f32x4 pv;
#pragma unroll
        for (int r = 0; r < 4; ++r)
          pv[r] = __builtin_amdgcn_exp2f(sacc[fm][fn][r] - mcur);
        vs_ += pv;
        f16x2 plo = cvt_pk(pv[0], pv[1]);
        f16x2 phi = cvt_pk(pv[2], pv[3]);
        f16x4 ph = {plo[0], plo[1], phi[0], phi[1]};
        p16[fm][fn] = ph;
      }
      float rs = (vs_[0] + vs_[1]) + (vs_[2] + vs_[3]);
      rs += __shfl_xor(rs, 16, 64);
      rs += __shfl_xor(rs, 32, 64);
      lrun[fm] += rs;
    }

    // P -> per-wave LDS (write pos: chunk fn*2+(g>>1), off (g&1)*4 == m=4g+r)
#pragma unroll
    for (int fm = 0; fm < 2; ++fm) {
      int q32 = fm * 16 + lo;
      int sw = q32 & 7;
#pragma unroll
      for (int fn = 0; fn < 4; ++fn) {
        int cq = fn * 2 + (g >> 1);
        *(f16x4*)&psw[q32 * 64 + ((cq ^ sw) * 8) + (g & 1) * 4] = p16[fm][fn];
      }
    }
    // within-wave DS ops stay ordered; no barrier needed
    __builtin_amdgcn_s_setprio(1);  // T5: favor PV MFMA cluster
#pragma unroll
    for (int kk = 0; kk < 2; ++kk) {
      f16x8 pa[2], vf[4];
#pragma unroll
      for (int fm = 0; fm < 2; ++fm) {
        int q32 = fm * 16 + lo;
        pa[fm] =
            *(const f16x8*)&psw[q32 * 64 + (((kk * 4 + g) ^ (q32 & 7)) * 8)];
      }
#pragma unroll
      for (int fd = 0; fd < 4; ++fd) {
        int d = fd * 16 + lo;
        vf[fd] = *(const f16x8*)&Vb[d * 64 + (((kk * 4 + g) ^ (d & 7)) * 8)];
      }
#pragma unroll
      for (int fm = 0; fm < 2; ++fm)
#pragma unroll
        for (int fd = 0; fd < 4; ++fd)
          oacc[fm][fd] = mfma16(vf[fd], pa[fm], oacc[fm][fd]);
    }
    __builtin_amdgcn_s_setprio(0);
  };

  STAGE_KV(0, kb_g, vb_g);
  const f16* kn = kb_g + 64 * 1536;
  const f16* vn = vb_g + 64;
  __syncthreads();  // drains prologue stage + bias writes

#pragma unroll 1
  for (int mt2 = 0; mt2 < 16; ++mt2) {
    // half A: compute buf0 (tile 2*mt2), prefetch tile 2*mt2+1 -> buf1
    STAGE_KV(1, kn, vn);
    kn += 64 * 1536;
    vn += 64;
    tile_body(&Kd[0][0], &Vd[0][0], mt2 * 128);
    __syncthreads();
    // half B: compute buf1 (tile 2*mt2+1), prefetch tile 2*mt2+2 -> buf0
    if (mt2 < 15) {
      STAGE_KV(0, kn, vn);
      kn += 64 * 1536;
      vn += 64;
    }
    tile_body(&Kd[1][0], &Vd[1][0], mt2 * 128 + 64);
    __syncthreads();
  }

  // epilogue: O /= l; oacc quads are d-contiguous -> f16x4 LDS writes
  f16* T2 = &Kd[0][0];  // [128 q][64 d] swz (chunk ^ q&7), overlays Kd+Vd
#pragma unroll
  for (int fm = 0; fm < 2; ++fm) {
    float rcp = 1.f / lrun[fm];
    int q = w * 32 + fm * 16 + lo;
    int sw = q & 7;
#pragma unroll
    for (int fd = 0; fd < 4; ++fd) {
      int c8 = fd * 2 + (g >> 1);
      f16x4 o4 = {(f16)(oacc[fm][fd][0] * rcp), (f16)(oacc[fm][fd][1] * rcp),
                  (f16)(oacc[fm][fd][2] * rcp), (f16)(oacc[fm][fd][3] * rcp)};
      *(f16x4*)&T2[q * 64 + ((c8 ^ sw) * 8) + (g & 1) * 4] = o4;
    }
  }
  __syncthreads();
  f16* cb = ctxt + (size_t)b * 2048 * 768;
  int qrow = t >> 1, half = t & 1;
#pragma unroll
  for (int c = 0; c < 4; ++c) {
    int c8 = half * 4 + c;
    f16x8 v = *(const f16x8*)&T2[qrow * 64 + ((c8 ^ (qrow & 7)) * 8)];
    *(f16x8*)&cb[(size_t)(n0 + qrow) * 768 + h * 64 + c8 * 8] = v;
  }
#undef STAGE_KV
}

// ---------------------------------------------------------------- launch
// ws total = 27,525,120 f16 = 52.5 MiB. Ctxt aliases Xt (dead after GEMM1).
extern "C" void kernel_launch(void* const* d_in, const int* in_sizes, int n_in,
                              void* d_out, int out_size, void* d_ws,
                              size_t ws_size, hipStream_t stream) {
  const float* x  = (const float*)d_in[0];
  const float* Wq = (const float*)d_in[1];
  const float* Wk = (const float*)d_in[2];
  const float* Wv = (const float*)d_in[3];
  const float* Wo = (const float*)d_in[4];
  const int* mask = (const int*)d_in[5];
  float* out = (float*)d_out;

  f16* Xt   = (f16*)d_ws;            // 6291456  (B,2048,768) -- reused as Ctxt
  f16* Wcat = Xt + 6291456;          // 1769472  (2304,768)  Wq|Wk|Wv rows
  f16* Wob  = Wcat + 1769472;        // 589824   (768,768)
  f16* QKt  = Wob + 589824;          // 12582912 (B,2048,1536)
  f16* Vbuf = QKt + 12582912;        // 6291456  (B,768,2048)
  f16* Ctxt = Xt;                    // alias    (B,2048,768)

  convert_w<<<2304, 256, 0, stream>>>(Wq, Wk, Wv, Wo, Wcat, Wob);
  transpose_x<<<dim3(32, 12, 4), 256, 0, stream>>>(x, Xt);
  gemm_kernel<<<dim3(16, 18, 4), 256, 0, stream>>>(Wcat, Xt, QKt, Vbuf, nullptr, 0);
  attn_kernel<<<dim3(16, 48), 256, 0, stream>>>(QKt, Vbuf, mask, Ctxt);
  gemm_kernel<<<dim3(16, 6, 4), 256, 0, stream>>>(Wob, Ctxt, nullptr, nullptr, out, 1);
}